// Round 1
// baseline (162.222 us; speedup 1.0000x reference)
//
#include <hip/hip_runtime.h>

typedef short bf16x8 __attribute__((ext_vector_type(8)));
typedef float f32x4  __attribute__((ext_vector_type(4)));

#define CAP 12

// ws layout (bytes)
#define WS_LOSS 0
#define WS_DONE 8
#define WS_EBF  64      // 1024*64 bf16 (permuted) = 131072 B

// dynamic LDS carve (bytes) — 23.5 KB total -> 4 blocks/CU
#define L_ZL     0        // 64 dims x (64 pos + pad) fp32 = 64*65*4 = 16640
#define L_MARG   16640    // 64*4 = 256
#define L_CCNT   16896    // 256
#define L_KCH    17152    // 256
#define L_RM4    17408    // 64 pos x 4 K-quarters = 1024
#define L_CBS    18432    // 4 x 64 rescore partial scores = 1024
#define L_CBK    19456    // 4 x 64 rescore partial codes  = 1024
#define L_CSLOT  20480    // 64*CAP*4 = 3072
#define L_TOTAL  23552

__device__ __forceinline__ unsigned short f2bf(float f) {
    unsigned u = __float_as_uint(f);
    return (unsigned short)((u + 0x7fffu + ((u >> 16) & 1u)) >> 16);  // RTNE
}

// numpy pairwise sum (n=64): 8 accumulators, ((r0+r1)+(r2+r3))+((r4+r5)+(r6+r7)).
__device__ __forceinline__ float np_pairwise_sumsq64(const float* a) {
    float r[8];
    #pragma unroll
    for (int j = 0; j < 8; ++j) r[j] = __fmul_rn(a[j], a[j]);
    #pragma unroll
    for (int i = 8; i < 64; i += 8)
        #pragma unroll
        for (int j = 0; j < 8; ++j)
            r[j] = __fadd_rn(r[j], __fmul_rn(a[i + j], a[i + j]));
    return __fadd_rn(
        __fadd_rn(__fadd_rn(r[0], r[1]), __fadd_rn(r[2], r[3])),
        __fadd_rn(__fadd_rn(r[4], r[5]), __fadd_rn(r[6], r[7])));
}

// K1: bf16 codebook in MFMA-B-fragment-permuted layout + zero loss/done.
// ebf[tile(64)][chunk j(8)][row r(16)][8 bf16], code = tile*16+r.
__global__ __launch_bounds__(256) void prep_kernel(
    const float* __restrict__ emb, unsigned short* __restrict__ ebf,
    float* __restrict__ loss, int* __restrict__ done)
{
    int k = blockIdx.x * 256 + threadIdx.x;
    if (k == 0) { *loss = 0.0f; *done = 0; }
    if (k < 1024) {
        float e[64];
        #pragma unroll
        for (int l = 0; l < 64; ++l) e[l] = emb[k * 64 + l];
        int tile = k >> 4, r = k & 15;
        #pragma unroll
        for (int j = 0; j < 8; ++j) {
            bf16x8 v;
            #pragma unroll
            for (int m = 0; m < 8; ++m) v[m] = (short)f2bf(e[j * 8 + m]);
            *(bf16x8*)(ebf + tile * 1024 + j * 128 + r * 8) = v;
        }
    }
}

// K2: fused VQ, occupancy-restructured.
// 1024 blocks x 256 thr (4 waves), 64 pos/block. No codebook in LDS — B-frags
// stream from global (L2-resident 128 KB, depth-4 prefetch). Wave wv owns
// K-quarter kq=wv (256 codes, 16 tiles). ze tile staged once in LDS (stride 65).
// 4 blocks/CU = 16 waves/CU in independent barrier domains.
__global__ __launch_bounds__(256)
__attribute__((amdgpu_waves_per_eu(4)))
void vq_kernel(
    const float* __restrict__ ze, const float* __restrict__ emb,
    const unsigned short* __restrict__ ebf,
    float* __restrict__ out_zq, float* __restrict__ out_idxf,
    float* __restrict__ loss, int* __restrict__ done,
    float* __restrict__ out_loss)
{
    extern __shared__ char smem[];
    float* zl     = (float*)(smem + L_ZL);
    float* marg_l = (float*)(smem + L_MARG);
    int*   ccnt   = (int*)(smem + L_CCNT);
    int*   kch    = (int*)(smem + L_KCH);
    float* rm4    = (float*)(smem + L_RM4);
    float* cbs    = (float*)(smem + L_CBS);
    int*   cbk    = (int*)(smem + L_CBK);
    int*   cslot  = (int*)(smem + L_CSLOT);

    const int t = threadIdx.x;
    const int n0 = blockIdx.x * 64;
    const int gbase = (n0 >> 12) * 262144 + (n0 & 4095);

    // ---- stage ze block -> LDS fp32 (verbatim bits; stride 65 kills conflicts)
    {
        const int p4 = (t & 15) * 4, lg = t >> 4;
        #pragma unroll
        for (int i = 0; i < 4; ++i) {
            const int l = lg + i * 16;
            const float4 v = *(const float4*)(ze + gbase + l * 4096 + p4);
            zl[l * 65 + p4 + 0] = v.x;
            zl[l * 65 + p4 + 1] = v.y;
            zl[l * 65 + p4 + 2] = v.z;
            zl[l * 65 + p4 + 3] = v.w;
        }
        if (t < 64) ccnt[t] = 0;
    }
    __syncthreads();

    // ---- margins (R5/R6-proven filter margin), from LDS
    if (t < 64) {
        float S = 0.0f;
        #pragma unroll
        for (int l = 0; l < 64; ++l) S += fabsf(zl[l * 65 + t]);
        marg_l[t] = 1.67e-5f * S + 2.0e-4f;
    }

    const int lane = t & 63, kq = t >> 6;
    const int r = lane & 15, q = lane >> 4;

    // ---- A-fragments from LDS: A[m=rg*16+r][k=q*8+j] (2-way banks max)
    bf16x8 a0[4], a1[4];
    #pragma unroll
    for (int rg = 0; rg < 4; ++rg) {
        #pragma unroll
        for (int j = 0; j < 8; ++j) {
            a0[rg][j] = (short)f2bf(zl[(q * 8 + j) * 65 + rg * 16 + r]);
            a1[rg][j] = (short)f2bf(zl[(32 + q * 8 + j) * 65 + rg * 16 + r]);
        }
    }

    // global B pointer for this wave's K-quarter (16 tiles of 16 codes)
    const unsigned short* gb = ebf + kq * 16384 + q * 128 + r * 8;

    // ---- pass 1: per-row max of c = z.e over this wave's 256 codes
    float rm[16];
    #pragma unroll
    for (int i = 0; i < 16; ++i) rm[i] = -1e30f;
    {
        bf16x8 pb0[4], pb1[4];
        #pragma unroll
        for (int i = 0; i < 4; ++i) {
            pb0[i] = *(const bf16x8*)(gb + i * 1024);
            pb1[i] = *(const bf16x8*)(gb + i * 1024 + 512);
        }
        #pragma unroll 4
        for (int tt = 0; tt < 16; ++tt) {
            bf16x8 b0 = pb0[tt & 3], b1 = pb1[tt & 3];
            int nt = tt + 4; if (nt > 15) nt = 15;
            pb0[tt & 3] = *(const bf16x8*)(gb + nt * 1024);
            pb1[tt & 3] = *(const bf16x8*)(gb + nt * 1024 + 512);
            #pragma unroll
            for (int rg = 0; rg < 4; ++rg) {
                f32x4 c = {0.f, 0.f, 0.f, 0.f};
                c = __builtin_amdgcn_mfma_f32_16x16x32_bf16(a0[rg], b0, c, 0, 0, 0);
                c = __builtin_amdgcn_mfma_f32_16x16x32_bf16(a1[rg], b1, c, 0, 0, 0);
                #pragma unroll
                for (int i = 0; i < 4; ++i)
                    rm[rg * 4 + i] = fmaxf(rm[rg * 4 + i], c[i]);
            }
        }
    }
    // reduce over the 16 code-lanes, publish per-quarter rowmax
    #pragma unroll
    for (int j = 0; j < 16; ++j) {
        float v = rm[j];
        v = fmaxf(v, __shfl_xor(v, 1, 16));
        v = fmaxf(v, __shfl_xor(v, 2, 16));
        v = fmaxf(v, __shfl_xor(v, 4, 16));
        v = fmaxf(v, __shfl_xor(v, 8, 16));
        const int row = (j >> 2) * 16 + q * 4 + (j & 3);
        if (r == 0) rm4[row * 4 + kq] = v;
    }
    __syncthreads();

    // merged threshold: candidate iff c >= maxc - marg/2 (global max over 4 quarters)
    float thr[16];
    #pragma unroll
    for (int j = 0; j < 16; ++j) {
        const int row = (j >> 2) * 16 + q * 4 + (j & 3);
        const float maxc = fmaxf(fmaxf(rm4[row * 4 + 0], rm4[row * 4 + 1]),
                                 fmaxf(rm4[row * 4 + 2], rm4[row * 4 + 3]));
        thr[j] = maxc - 0.5f * marg_l[row];
    }

    // ---- pass 2: collect candidates
    {
        bf16x8 pb0[4], pb1[4];
        #pragma unroll
        for (int i = 0; i < 4; ++i) {
            pb0[i] = *(const bf16x8*)(gb + i * 1024);
            pb1[i] = *(const bf16x8*)(gb + i * 1024 + 512);
        }
        #pragma unroll 4
        for (int tt = 0; tt < 16; ++tt) {
            bf16x8 b0 = pb0[tt & 3], b1 = pb1[tt & 3];
            int nt = tt + 4; if (nt > 15) nt = 15;
            pb0[tt & 3] = *(const bf16x8*)(gb + nt * 1024);
            pb1[tt & 3] = *(const bf16x8*)(gb + nt * 1024 + 512);
            const int code = kq * 256 + tt * 16 + r;
            #pragma unroll
            for (int rg = 0; rg < 4; ++rg) {
                f32x4 c = {0.f, 0.f, 0.f, 0.f};
                c = __builtin_amdgcn_mfma_f32_16x16x32_bf16(a0[rg], b0, c, 0, 0, 0);
                c = __builtin_amdgcn_mfma_f32_16x16x32_bf16(a1[rg], b1, c, 0, 0, 0);
                #pragma unroll
                for (int i = 0; i < 4; ++i) {
                    if (c[i] >= thr[rg * 4 + i]) {
                        const int pp = rg * 16 + q * 4 + i;
                        const int ci = atomicAdd(&ccnt[pp], 1);
                        if (ci < CAP) cslot[pp * CAP + ci] = code;
                    }
                }
            }
        }
    }
    __syncthreads();

    // ---- exact fp32 numpy rescore, 4 threads/position (candidate-strided)
    {
        const int p = t & 63, cl = t >> 6;
        int cnt = ccnt[p]; if (cnt > CAP) cnt = CAP;
        float z[64];
        #pragma unroll
        for (int l = 0; l < 64; ++l) z[l] = zl[l * 65 + p];   // verbatim fp32
        const float znorm = np_pairwise_sumsq64(z);
        float best = 1e30f; int bk = 1 << 20;
        for (int c = cl; c < cnt; c += 4) {
            const int k = cslot[p * CAP + c];
            float e[64];
            const float4* er = (const float4*)(emb + k * 64);
            #pragma unroll
            for (int j = 0; j < 16; ++j) {
                float4 v = er[j];
                e[4*j] = v.x; e[4*j+1] = v.y; e[4*j+2] = v.z; e[4*j+3] = v.w;
            }
            const float en = np_pairwise_sumsq64(e);        // bit-exact numpy enorm
            float acc = 0.0f;
            #pragma unroll
            for (int l = 0; l < 64; ++l) acc = fmaf(z[l], e[l], acc);  // sgemm order
            const float sc = __fsub_rn(__fadd_rn(znorm, en), __fmul_rn(2.0f, acc));
            if (sc < best || (sc == best && k < bk)) { best = sc; bk = k; }
        }
        cbs[cl * 64 + p] = best;
        cbk[cl * 64 + p] = bk;
    }
    __syncthreads();

    // ---- lex-(score,k) merge of 4 partials, write idx
    if (t < 64) {
        float best = cbs[t]; int bk = cbk[t];
        #pragma unroll
        for (int i = 1; i < 4; ++i) {
            const float sc = cbs[i * 64 + t]; const int k = cbk[i * 64 + t];
            if (sc < best || (sc == best && k < bk)) { best = sc; bk = k; }
        }
        kch[t] = bk;
        out_idxf[n0 + t] = (float)bk;
    }
    __syncthreads();

    // ---- epilogue: 256 threads, dims split (h = t>>6, 16 dims each)
    {
        const int p = t & 63, h = t >> 6;
        const int bk = kch[p];
        const float* er = emb + bk * 64 + h * 16;
        float* op = out_zq + gbase + p + (h * 16) * 4096;
        float ls = 0.0f;
        #pragma unroll
        for (int j = 0; j < 16; ++j) {
            const float qv = er[j];
            const float zv = zl[(h * 16 + j) * 65 + p];
            op[j * 4096] = qv;
            const float d = qv - zv;
            ls = fmaf(d, d, ls);
        }
        #pragma unroll
        for (int off = 32; off > 0; off >>= 1) ls += __shfl_down(ls, off, 64);
        if (lane == 0) atomicAdd(loss, ls);
    }

    // ---- last block finalizes loss (device-scope atomics)
    __syncthreads();
    if (t == 0) {
        __threadfence();
        int old = atomicAdd(done, 1);
        if (old == (int)gridDim.x - 1) {
            __threadfence();
            float total = atomicAdd(loss, 0.0f);   // coherent read
            *out_loss = 1.25f * total / 4194304.0f;
        }
    }
}

extern "C" void kernel_launch(void* const* d_in, const int* in_sizes, int n_in,
                              void* d_out, int out_size, void* d_ws, size_t ws_size,
                              hipStream_t stream)
{
    const float* ze  = (const float*)d_in[0];   // (16,64,64,64) fp32
    const float* emb = (const float*)d_in[1];   // (1024,64) fp32
    float* out = (float*)d_out;
    float* out_zq   = out;                 // 4194304
    float* out_loss = out + 4194304;       // 1
    float* out_idxf = out + 4194305;       // 65536

    char* w = (char*)d_ws;
    float*          ws_loss = (float*)(w + WS_LOSS);
    int*            ws_done = (int*)(w + WS_DONE);
    unsigned short* ebf     = (unsigned short*)(w + WS_EBF);

    prep_kernel<<<4, 256, 0, stream>>>(emb, ebf, ws_loss, ws_done);
    vq_kernel<<<1024, 256, L_TOTAL, stream>>>(ze, emb, ebf, out_zq, out_idxf,
                                              ws_loss, ws_done, out_loss);
}

// Round 2
// 161.622 us; speedup vs baseline: 1.0037x; 1.0037x over previous
//
#include <hip/hip_runtime.h>

typedef short bf16x8 __attribute__((ext_vector_type(8)));
typedef float f32x4  __attribute__((ext_vector_type(4)));

#define CAP 12

// ws layout (bytes)
#define WS_LOSS 0
#define WS_DONE 8
#define WS_EBF  64      // 1024*64 bf16 (permuted) = 131072 B

// dynamic LDS carve (bytes) — 23.5 KB total -> 4 blocks/CU co-resident
#define L_ZL     0        // 64 dims x (64 pos + pad) fp32 = 64*65*4 = 16640
#define L_MARG   16640    // 64*4 = 256
#define L_CCNT   16896    // 256
#define L_KCH    17152    // 256
#define L_RM4    17408    // 64 pos x 4 K-quarters = 1024
#define L_CBS    18432    // 4 x 64 rescore partial scores = 1024
#define L_CBK    19456    // 4 x 64 rescore partial codes  = 1024
#define L_CSLOT  20480    // 64*CAP*4 = 3072
#define L_TOTAL  23552

__device__ __forceinline__ unsigned short f2bf(float f) {
    unsigned u = __float_as_uint(f);
    return (unsigned short)((u + 0x7fffu + ((u >> 16) & 1u)) >> 16);  // RTNE
}

// numpy pairwise sum (n=64): 8 accumulators, ((r0+r1)+(r2+r3))+((r4+r5)+(r6+r7)).
__device__ __forceinline__ float np_pairwise_sumsq64(const float* a) {
    float r[8];
    #pragma unroll
    for (int j = 0; j < 8; ++j) r[j] = __fmul_rn(a[j], a[j]);
    #pragma unroll
    for (int i = 8; i < 64; i += 8)
        #pragma unroll
        for (int j = 0; j < 8; ++j)
            r[j] = __fadd_rn(r[j], __fmul_rn(a[i + j], a[i + j]));
    return __fadd_rn(
        __fadd_rn(__fadd_rn(r[0], r[1]), __fadd_rn(r[2], r[3])),
        __fadd_rn(__fadd_rn(r[4], r[5]), __fadd_rn(r[6], r[7])));
}

// K1: bf16 codebook in MFMA-B-fragment-permuted layout + zero loss/done.
// ebf[tile(64)][chunk j(8)][row r(16)][8 bf16], code = tile*16+r.
__global__ __launch_bounds__(256) void prep_kernel(
    const float* __restrict__ emb, unsigned short* __restrict__ ebf,
    float* __restrict__ loss, int* __restrict__ done)
{
    int k = blockIdx.x * 256 + threadIdx.x;
    if (k == 0) { *loss = 0.0f; *done = 0; }
    if (k < 1024) {
        float e[64];
        #pragma unroll
        for (int l = 0; l < 64; ++l) e[l] = emb[k * 64 + l];
        int tile = k >> 4, r = k & 15;
        #pragma unroll
        for (int j = 0; j < 8; ++j) {
            bf16x8 v;
            #pragma unroll
            for (int m = 0; m < 8; ++m) v[m] = (short)f2bf(e[j * 8 + m]);
            *(bf16x8*)(ebf + tile * 1024 + j * 128 + r * 8) = v;
        }
    }
}

// K2: fused VQ. 1024 blocks x 256 thr (4 waves), 64 pos/block.
// B-frags stream from global ebf (L2-resident 128 KB, depth-4 reg prefetch).
// Wave kq owns a 256-code K-quarter. ze tile staged once in LDS (stride 65).
// __launch_bounds__(256,4): 4 blocks/CU = 16 waves/CU, VGPR cap 128 (no spill
// — R1's waves_per_eu(4) squeezed to 64 VGPRs and spilled the pass loops:
// WRITE_SIZE 16.7->22.3 MB scratch traffic, MfmaUtil down. This fixes that.)
__global__ __launch_bounds__(256, 4)
void vq_kernel(
    const float* __restrict__ ze, const float* __restrict__ emb,
    const unsigned short* __restrict__ ebf,
    float* __restrict__ out_zq, float* __restrict__ out_idxf,
    float* __restrict__ loss, int* __restrict__ done,
    float* __restrict__ out_loss)
{
    extern __shared__ char smem[];
    float* zl     = (float*)(smem + L_ZL);
    float* marg_l = (float*)(smem + L_MARG);
    int*   ccnt   = (int*)(smem + L_CCNT);
    int*   kch    = (int*)(smem + L_KCH);
    float* rm4    = (float*)(smem + L_RM4);
    float* cbs    = (float*)(smem + L_CBS);
    int*   cbk    = (int*)(smem + L_CBK);
    int*   cslot  = (int*)(smem + L_CSLOT);

    const int t = threadIdx.x;
    const int n0 = blockIdx.x * 64;
    const int gbase = (n0 >> 12) * 262144 + (n0 & 4095);

    // ---- stage ze block -> LDS fp32 (verbatim bits; stride 65 kills conflicts)
    {
        const int p4 = (t & 15) * 4, lg = t >> 4;
        #pragma unroll
        for (int i = 0; i < 4; ++i) {
            const int l = lg + i * 16;
            const float4 v = *(const float4*)(ze + gbase + l * 4096 + p4);
            zl[l * 65 + p4 + 0] = v.x;
            zl[l * 65 + p4 + 1] = v.y;
            zl[l * 65 + p4 + 2] = v.z;
            zl[l * 65 + p4 + 3] = v.w;
        }
        if (t < 64) ccnt[t] = 0;
    }
    __syncthreads();

    // ---- margins (R5/R6-proven filter margin), from LDS
    if (t < 64) {
        float S = 0.0f;
        #pragma unroll
        for (int l = 0; l < 64; ++l) S += fabsf(zl[l * 65 + t]);
        marg_l[t] = 1.67e-5f * S + 2.0e-4f;
    }

    const int lane = t & 63, kq = t >> 6;
    const int r = lane & 15, q = lane >> 4;

    // ---- A-fragments from LDS: A[m=rg*16+r][k=q*8+j] (2-way banks max)
    bf16x8 a0[4], a1[4];
    #pragma unroll
    for (int rg = 0; rg < 4; ++rg) {
        #pragma unroll
        for (int j = 0; j < 8; ++j) {
            a0[rg][j] = (short)f2bf(zl[(q * 8 + j) * 65 + rg * 16 + r]);
            a1[rg][j] = (short)f2bf(zl[(32 + q * 8 + j) * 65 + rg * 16 + r]);
        }
    }

    // global B pointer for this wave's K-quarter (16 tiles of 16 codes)
    const unsigned short* gb = ebf + kq * 16384 + q * 128 + r * 8;

    // ---- pass 1: per-row max of c = z.e over this wave's 256 codes
    float rm[16];
    #pragma unroll
    for (int i = 0; i < 16; ++i) rm[i] = -1e30f;
    {
        bf16x8 pb0[4], pb1[4];
        #pragma unroll
        for (int i = 0; i < 4; ++i) {
            pb0[i] = *(const bf16x8*)(gb + i * 1024);
            pb1[i] = *(const bf16x8*)(gb + i * 1024 + 512);
        }
        #pragma unroll 4
        for (int tt = 0; tt < 16; ++tt) {
            bf16x8 b0 = pb0[tt & 3], b1 = pb1[tt & 3];
            int nt = tt + 4; if (nt > 15) nt = 15;
            pb0[tt & 3] = *(const bf16x8*)(gb + nt * 1024);
            pb1[tt & 3] = *(const bf16x8*)(gb + nt * 1024 + 512);
            #pragma unroll
            for (int rg = 0; rg < 4; ++rg) {
                f32x4 c = {0.f, 0.f, 0.f, 0.f};
                c = __builtin_amdgcn_mfma_f32_16x16x32_bf16(a0[rg], b0, c, 0, 0, 0);
                c = __builtin_amdgcn_mfma_f32_16x16x32_bf16(a1[rg], b1, c, 0, 0, 0);
                #pragma unroll
                for (int i = 0; i < 4; ++i)
                    rm[rg * 4 + i] = fmaxf(rm[rg * 4 + i], c[i]);
            }
        }
    }
    // reduce over the 16 code-lanes, publish per-quarter rowmax
    #pragma unroll
    for (int j = 0; j < 16; ++j) {
        float v = rm[j];
        v = fmaxf(v, __shfl_xor(v, 1, 16));
        v = fmaxf(v, __shfl_xor(v, 2, 16));
        v = fmaxf(v, __shfl_xor(v, 4, 16));
        v = fmaxf(v, __shfl_xor(v, 8, 16));
        const int row = (j >> 2) * 16 + q * 4 + (j & 3);
        if (r == 0) rm4[row * 4 + kq] = v;
    }
    __syncthreads();

    // merged threshold: candidate iff c >= maxc - marg/2 (global max over 4 quarters)
    float thr[16];
    #pragma unroll
    for (int j = 0; j < 16; ++j) {
        const int row = (j >> 2) * 16 + q * 4 + (j & 3);
        const float maxc = fmaxf(fmaxf(rm4[row * 4 + 0], rm4[row * 4 + 1]),
                                 fmaxf(rm4[row * 4 + 2], rm4[row * 4 + 3]));
        thr[j] = maxc - 0.5f * marg_l[row];
    }

    // ---- pass 2: collect candidates
    {
        bf16x8 pb0[4], pb1[4];
        #pragma unroll
        for (int i = 0; i < 4; ++i) {
            pb0[i] = *(const bf16x8*)(gb + i * 1024);
            pb1[i] = *(const bf16x8*)(gb + i * 1024 + 512);
        }
        #pragma unroll 4
        for (int tt = 0; tt < 16; ++tt) {
            bf16x8 b0 = pb0[tt & 3], b1 = pb1[tt & 3];
            int nt = tt + 4; if (nt > 15) nt = 15;
            pb0[tt & 3] = *(const bf16x8*)(gb + nt * 1024);
            pb1[tt & 3] = *(const bf16x8*)(gb + nt * 1024 + 512);
            const int code = kq * 256 + tt * 16 + r;
            #pragma unroll
            for (int rg = 0; rg < 4; ++rg) {
                f32x4 c = {0.f, 0.f, 0.f, 0.f};
                c = __builtin_amdgcn_mfma_f32_16x16x32_bf16(a0[rg], b0, c, 0, 0, 0);
                c = __builtin_amdgcn_mfma_f32_16x16x32_bf16(a1[rg], b1, c, 0, 0, 0);
                #pragma unroll
                for (int i = 0; i < 4; ++i) {
                    if (c[i] >= thr[rg * 4 + i]) {
                        const int pp = rg * 16 + q * 4 + i;
                        const int ci = atomicAdd(&ccnt[pp], 1);
                        if (ci < CAP) cslot[pp * CAP + ci] = code;
                    }
                }
            }
        }
    }
    __syncthreads();

    // ---- exact fp32 numpy rescore, 4 threads/position (candidate-strided).
    // e[] streamed in float4 pairs (8 live floats) to keep VGPR peak low;
    // op order identical to numpy pairwise sumsq + sequential fmaf dot.
    {
        const int p = t & 63, cl = t >> 6;
        int cnt = ccnt[p]; if (cnt > CAP) cnt = CAP;
        float z[64];
        #pragma unroll
        for (int l = 0; l < 64; ++l) z[l] = zl[l * 65 + p];   // verbatim fp32
        const float znorm = np_pairwise_sumsq64(z);
        float best = 1e30f; int bk = 1 << 20;
        for (int c = cl; c < cnt; c += 4) {
            const int k = cslot[p * CAP + c];
            const float4* er = (const float4*)(emb + k * 64);
            float rr[8];
            float acc = 0.0f;
            #pragma unroll
            for (int ch = 0; ch < 8; ++ch) {
                const float4 va = er[2 * ch];
                const float4 vb = er[2 * ch + 1];
                float e0 = va.x, e1 = va.y, e2 = va.z, e3 = va.w;
                float e4 = vb.x, e5 = vb.y, e6 = vb.z, e7 = vb.w;
                if (ch == 0) {
                    rr[0] = __fmul_rn(e0, e0); rr[1] = __fmul_rn(e1, e1);
                    rr[2] = __fmul_rn(e2, e2); rr[3] = __fmul_rn(e3, e3);
                    rr[4] = __fmul_rn(e4, e4); rr[5] = __fmul_rn(e5, e5);
                    rr[6] = __fmul_rn(e6, e6); rr[7] = __fmul_rn(e7, e7);
                } else {
                    rr[0] = __fadd_rn(rr[0], __fmul_rn(e0, e0));
                    rr[1] = __fadd_rn(rr[1], __fmul_rn(e1, e1));
                    rr[2] = __fadd_rn(rr[2], __fmul_rn(e2, e2));
                    rr[3] = __fadd_rn(rr[3], __fmul_rn(e3, e3));
                    rr[4] = __fadd_rn(rr[4], __fmul_rn(e4, e4));
                    rr[5] = __fadd_rn(rr[5], __fmul_rn(e5, e5));
                    rr[6] = __fadd_rn(rr[6], __fmul_rn(e6, e6));
                    rr[7] = __fadd_rn(rr[7], __fmul_rn(e7, e7));
                }
                acc = fmaf(z[8 * ch + 0], e0, acc);
                acc = fmaf(z[8 * ch + 1], e1, acc);
                acc = fmaf(z[8 * ch + 2], e2, acc);
                acc = fmaf(z[8 * ch + 3], e3, acc);
                acc = fmaf(z[8 * ch + 4], e4, acc);
                acc = fmaf(z[8 * ch + 5], e5, acc);
                acc = fmaf(z[8 * ch + 6], e6, acc);
                acc = fmaf(z[8 * ch + 7], e7, acc);
            }
            const float en = __fadd_rn(
                __fadd_rn(__fadd_rn(rr[0], rr[1]), __fadd_rn(rr[2], rr[3])),
                __fadd_rn(__fadd_rn(rr[4], rr[5]), __fadd_rn(rr[6], rr[7])));
            const float sc = __fsub_rn(__fadd_rn(znorm, en), __fmul_rn(2.0f, acc));
            if (sc < best || (sc == best && k < bk)) { best = sc; bk = k; }
        }
        cbs[cl * 64 + p] = best;
        cbk[cl * 64 + p] = bk;
    }
    __syncthreads();

    // ---- lex-(score,k) merge of 4 partials, write idx
    if (t < 64) {
        float best = cbs[t]; int bk = cbk[t];
        #pragma unroll
        for (int i = 1; i < 4; ++i) {
            const float sc = cbs[i * 64 + t]; const int k = cbk[i * 64 + t];
            if (sc < best || (sc == best && k < bk)) { best = sc; bk = k; }
        }
        kch[t] = bk;
        out_idxf[n0 + t] = (float)bk;
    }
    __syncthreads();

    // ---- epilogue: 256 threads, dims split (h = t>>6, 16 dims each)
    {
        const int p = t & 63, h = t >> 6;
        const int bk = kch[p];
        const float* er = emb + bk * 64 + h * 16;
        float* op = out_zq + gbase + p + (h * 16) * 4096;
        float ls = 0.0f;
        #pragma unroll
        for (int j = 0; j < 16; ++j) {
            const float qv = er[j];
            const float zv = zl[(h * 16 + j) * 65 + p];
            op[j * 4096] = qv;
            const float d = qv - zv;
            ls = fmaf(d, d, ls);
        }
        #pragma unroll
        for (int off = 32; off > 0; off >>= 1) ls += __shfl_down(ls, off, 64);
        if (lane == 0) atomicAdd(loss, ls);
    }

    // ---- last block finalizes loss (device-scope atomics)
    __syncthreads();
    if (t == 0) {
        __threadfence();
        int old = atomicAdd(done, 1);
        if (old == (int)gridDim.x - 1) {
            __threadfence();
            float total = atomicAdd(loss, 0.0f);   // coherent read
            *out_loss = 1.25f * total / 4194304.0f;
        }
    }
}

extern "C" void kernel_launch(void* const* d_in, const int* in_sizes, int n_in,
                              void* d_out, int out_size, void* d_ws, size_t ws_size,
                              hipStream_t stream)
{
    const float* ze  = (const float*)d_in[0];   // (16,64,64,64) fp32
    const float* emb = (const float*)d_in[1];   // (1024,64) fp32
    float* out = (float*)d_out;
    float* out_zq   = out;                 // 4194304
    float* out_loss = out + 4194304;       // 1
    float* out_idxf = out + 4194305;       // 65536

    char* w = (char*)d_ws;
    float*          ws_loss = (float*)(w + WS_LOSS);
    int*            ws_done = (int*)(w + WS_DONE);
    unsigned short* ebf     = (unsigned short*)(w + WS_EBF);

    prep_kernel<<<4, 256, 0, stream>>>(emb, ebf, ws_loss, ws_done);
    vq_kernel<<<1024, 256, L_TOTAL, stream>>>(ze, emb, ebf, out_zq, out_idxf,
                                              ws_loss, ws_done, out_loss);
}

// Round 3
// 160.121 us; speedup vs baseline: 1.0131x; 1.0094x over previous
//
#include <hip/hip_runtime.h>

typedef short bf16x8 __attribute__((ext_vector_type(8)));
typedef float f32x4  __attribute__((ext_vector_type(4)));

#define CAP 12

// ws layout (bytes)
#define WS_LOSS 0
#define WS_DONE 8
#define WS_EBF  64      // 1024*64 bf16 (permuted) = 131072 B

// dynamic LDS carve (bytes) — 155 KB, 1 block/CU (16 waves = 4/SIMD)
#define L_EBF    0        // 131072
#define L_MARG   131072   // 256*4 = 1024
#define L_CCNT   132096   // 1024
#define L_KCH    133120   // 1024
#define L_RM4    134144   // 256 pos x 4 K-quarters x 4B = 4096
#define L_CSLOT  138240   // 256*CAP*4 = 12288
#define L_CBS    150528   // 4 x 256 rescore partial scores = 4096
#define L_CBK    154624   // 4 x 256 rescore partial codes  = 4096
#define L_TOTAL  158720

__device__ __forceinline__ unsigned short f2bf(float f) {
    unsigned u = __float_as_uint(f);
    return (unsigned short)((u + 0x7fffu + ((u >> 16) & 1u)) >> 16);  // RTNE
}

// K1: bf16 codebook in MFMA-B-fragment-permuted layout + zero loss/done.
// ebf[tile(64)][chunk j(8)][row r(16)][8 bf16], code = tile*16+r.
// Lane-linear property: byte offset of lane (q*16+r) within a tile = lane*16.
__global__ __launch_bounds__(256) void prep_kernel(
    const float* __restrict__ emb, unsigned short* __restrict__ ebf,
    float* __restrict__ loss, int* __restrict__ done)
{
    int k = blockIdx.x * 256 + threadIdx.x;
    if (k == 0) { *loss = 0.0f; *done = 0; }
    if (k < 1024) {
        float e[64];
        #pragma unroll
        for (int l = 0; l < 64; ++l) e[l] = emb[k * 64 + l];
        int tile = k >> 4, r = k & 15;
        #pragma unroll
        for (int j = 0; j < 8; ++j) {
            bf16x8 v;
            #pragma unroll
            for (int m = 0; m < 8; ++m) v[m] = (short)f2bf(e[j * 8 + m]);
            *(bf16x8*)(ebf + tile * 1024 + j * 128 + r * 8) = v;
        }
    }
}

// K2: fused VQ — R0 structure (codebook in LDS, 256 pos/block, grid 256)
// widened to 1024 thr = 16 waves = 4 waves/SIMD. Waves = 4 pos-groups x
// 4 K-quarters (256 codes each); rowmax merged over 4 quarters in LDS.
// R2 lesson: B must stream from LDS, not L2 (VALUBusy flat at 11.7% across
// occupancy 16.5->28% proved wave-slots weren't binding; B-latency was).
__global__ __launch_bounds__(1024, 4)
void vq_kernel(
    const float* __restrict__ ze, const float* __restrict__ emb,
    const unsigned short* __restrict__ ebf,
    float* __restrict__ out_zq, float* __restrict__ out_idxf,
    float* __restrict__ loss, int* __restrict__ done,
    float* __restrict__ out_loss)
{
    extern __shared__ char smem[];
    unsigned short* ebf_l = (unsigned short*)(smem + L_EBF);
    float*          marg_l= (float*)(smem + L_MARG);
    int*            ccnt  = (int*)(smem + L_CCNT);
    int*            kch   = (int*)(smem + L_KCH);
    float*          rm4   = (float*)(smem + L_RM4);
    int*            cslot = (int*)(smem + L_CSLOT);
    float*          cbs   = (float*)(smem + L_CBS);
    int*            cbk   = (int*)(smem + L_CBK);

    const int t = threadIdx.x;
    const int n0 = blockIdx.x * 256;
    const int gbase = (n0 >> 12) * 262144 + (n0 & 4095);

    // ---- stage codebook -> LDS (all 1024 thr, 8 x 16B each, lane-linear) ----
    {
        const bf16x8* src = (const bf16x8*)ebf;
        bf16x8* dst = (bf16x8*)ebf_l;
        #pragma unroll 8
        for (int i = 0; i < 8; ++i) dst[t + i * 1024] = src[t + i * 1024];
    }
    // ---- margins (R5/R6-proven filter margin) by waves 0-3, from global ----
    if (t < 256) {
        const float* zp = ze + gbase + t;
        float S = 0.0f;
        #pragma unroll
        for (int l = 0; l < 64; ++l) S += fabsf(zp[l * 4096]);
        marg_l[t] = 1.67e-5f * S + 2.0e-4f;
        ccnt[t] = 0;
    }

    // ---- A-fragments straight from global ze (L2-hot): A[m][k=q*8+j] ----
    const int wv = t >> 6, lane = t & 63;
    const int r = lane & 15, q = lane >> 4;
    const int pg = wv & 3, kq = wv >> 2;
    const int wp = pg * 64;
    bf16x8 a0[4], a1[4];
    #pragma unroll
    for (int rg = 0; rg < 4; ++rg) {
        const float* zb = ze + gbase + wp + rg * 16 + r;
        #pragma unroll
        for (int j = 0; j < 8; ++j) {
            a0[rg][j] = (short)f2bf(zb[(q * 8 + j) * 4096]);
            a1[rg][j] = (short)f2bf(zb[(32 + q * 8 + j) * 4096]);
        }
    }
    __syncthreads();

    // this wave's K-quarter: 16 tiles of 16 codes, starting at tile kq*16
    const unsigned short* bptr = ebf_l + (kq * 16) * 1024 + q * 128 + r * 8;

    // ---- pass 1: per-row max of c = z.e over this wave's 256 codes ----
    float rm[16];
    #pragma unroll
    for (int i = 0; i < 16; ++i) rm[i] = -1e30f;
    {
        bf16x8 pb0[2], pb1[2];
        pb0[0] = *(const bf16x8*)(bptr);
        pb1[0] = *(const bf16x8*)(bptr + 512);
        pb0[1] = *(const bf16x8*)(bptr + 1024);
        pb1[1] = *(const bf16x8*)(bptr + 1536);
        #pragma unroll 4
        for (int tile = 0; tile < 16; ++tile) {
            bf16x8 b0 = pb0[tile & 1], b1 = pb1[tile & 1];
            int nt = tile + 2; if (nt > 15) nt = 15;
            pb0[tile & 1] = *(const bf16x8*)(bptr + nt * 1024);
            pb1[tile & 1] = *(const bf16x8*)(bptr + nt * 1024 + 512);
            #pragma unroll
            for (int rg = 0; rg < 4; ++rg) {
                f32x4 c = {0.f, 0.f, 0.f, 0.f};
                c = __builtin_amdgcn_mfma_f32_16x16x32_bf16(a0[rg], b0, c, 0, 0, 0);
                c = __builtin_amdgcn_mfma_f32_16x16x32_bf16(a1[rg], b1, c, 0, 0, 0);
                #pragma unroll
                for (int i = 0; i < 4; ++i)
                    rm[rg * 4 + i] = fmaxf(rm[rg * 4 + i], c[i]);
            }
        }
    }
    // reduce over the 16 code-lanes, publish per-K-quarter rowmax
    #pragma unroll
    for (int j = 0; j < 16; ++j) {
        float v = rm[j];
        v = fmaxf(v, __shfl_xor(v, 1, 16));
        v = fmaxf(v, __shfl_xor(v, 2, 16));
        v = fmaxf(v, __shfl_xor(v, 4, 16));
        v = fmaxf(v, __shfl_xor(v, 8, 16));
        const int row = wp + (j >> 2) * 16 + q * 4 + (j & 3);
        if (r == 0) rm4[row * 4 + kq] = v;
    }
    __syncthreads();

    // merged threshold: candidate iff c >= maxc - marg/2 (max over 4 quarters)
    float thr[16];
    #pragma unroll
    for (int j = 0; j < 16; ++j) {
        const int row = wp + (j >> 2) * 16 + q * 4 + (j & 3);
        const float maxc = fmaxf(fmaxf(rm4[row * 4 + 0], rm4[row * 4 + 1]),
                                 fmaxf(rm4[row * 4 + 2], rm4[row * 4 + 3]));
        thr[j] = maxc - 0.5f * marg_l[row];
    }

    // ---- pass 2: collect candidates ----
    {
        bf16x8 pb0[2], pb1[2];
        pb0[0] = *(const bf16x8*)(bptr);
        pb1[0] = *(const bf16x8*)(bptr + 512);
        pb0[1] = *(const bf16x8*)(bptr + 1024);
        pb1[1] = *(const bf16x8*)(bptr + 1536);
        #pragma unroll 4
        for (int tile = 0; tile < 16; ++tile) {
            bf16x8 b0 = pb0[tile & 1], b1 = pb1[tile & 1];
            int nt = tile + 2; if (nt > 15) nt = 15;
            pb0[tile & 1] = *(const bf16x8*)(bptr + nt * 1024);
            pb1[tile & 1] = *(const bf16x8*)(bptr + nt * 1024 + 512);
            const int code = kq * 256 + tile * 16 + r;
            #pragma unroll
            for (int rg = 0; rg < 4; ++rg) {
                f32x4 c = {0.f, 0.f, 0.f, 0.f};
                c = __builtin_amdgcn_mfma_f32_16x16x32_bf16(a0[rg], b0, c, 0, 0, 0);
                c = __builtin_amdgcn_mfma_f32_16x16x32_bf16(a1[rg], b1, c, 0, 0, 0);
                #pragma unroll
                for (int i = 0; i < 4; ++i) {
                    if (c[i] >= thr[rg * 4 + i]) {
                        const int pp = wp + rg * 16 + q * 4 + i;
                        const int ci = atomicAdd(&ccnt[pp], 1);
                        if (ci < CAP) cslot[pp * CAP + ci] = code;
                    }
                }
            }
        }
    }
    __syncthreads();

    // ---- exact fp32 numpy rescore, 4 threads/position (candidate-strided).
    // e[] streamed in float4 pairs; op order bit-identical to numpy
    // pairwise sumsq (8 accumulators) + sequential fmaf dot.
    {
        const int p = t & 255, cl = t >> 8;
        int cnt = ccnt[p]; if (cnt > CAP) cnt = CAP;
        float z[64];
        const float* zp = ze + gbase + p;
        #pragma unroll
        for (int l = 0; l < 64; ++l) z[l] = zp[l * 4096];   // L2/L3-hot reload
        float znorm;
        {
            float rz[8];
            #pragma unroll
            for (int j = 0; j < 8; ++j) rz[j] = __fmul_rn(z[j], z[j]);
            #pragma unroll
            for (int i = 8; i < 64; i += 8)
                #pragma unroll
                for (int j = 0; j < 8; ++j)
                    rz[j] = __fadd_rn(rz[j], __fmul_rn(z[i + j], z[i + j]));
            znorm = __fadd_rn(
                __fadd_rn(__fadd_rn(rz[0], rz[1]), __fadd_rn(rz[2], rz[3])),
                __fadd_rn(__fadd_rn(rz[4], rz[5]), __fadd_rn(rz[6], rz[7])));
        }
        float best = 1e30f; int bk = 1 << 20;
        for (int c = cl; c < cnt; c += 4) {
            const int k = cslot[p * CAP + c];
            const float4* er = (const float4*)(emb + k * 64);
            float rr[8];
            float acc = 0.0f;
            #pragma unroll
            for (int ch = 0; ch < 8; ++ch) {
                const float4 va = er[2 * ch];
                const float4 vb = er[2 * ch + 1];
                float e0 = va.x, e1 = va.y, e2 = va.z, e3 = va.w;
                float e4 = vb.x, e5 = vb.y, e6 = vb.z, e7 = vb.w;
                if (ch == 0) {
                    rr[0] = __fmul_rn(e0, e0); rr[1] = __fmul_rn(e1, e1);
                    rr[2] = __fmul_rn(e2, e2); rr[3] = __fmul_rn(e3, e3);
                    rr[4] = __fmul_rn(e4, e4); rr[5] = __fmul_rn(e5, e5);
                    rr[6] = __fmul_rn(e6, e6); rr[7] = __fmul_rn(e7, e7);
                } else {
                    rr[0] = __fadd_rn(rr[0], __fmul_rn(e0, e0));
                    rr[1] = __fadd_rn(rr[1], __fmul_rn(e1, e1));
                    rr[2] = __fadd_rn(rr[2], __fmul_rn(e2, e2));
                    rr[3] = __fadd_rn(rr[3], __fmul_rn(e3, e3));
                    rr[4] = __fadd_rn(rr[4], __fmul_rn(e4, e4));
                    rr[5] = __fadd_rn(rr[5], __fmul_rn(e5, e5));
                    rr[6] = __fadd_rn(rr[6], __fmul_rn(e6, e6));
                    rr[7] = __fadd_rn(rr[7], __fmul_rn(e7, e7));
                }
                acc = fmaf(z[8 * ch + 0], e0, acc);
                acc = fmaf(z[8 * ch + 1], e1, acc);
                acc = fmaf(z[8 * ch + 2], e2, acc);
                acc = fmaf(z[8 * ch + 3], e3, acc);
                acc = fmaf(z[8 * ch + 4], e4, acc);
                acc = fmaf(z[8 * ch + 5], e5, acc);
                acc = fmaf(z[8 * ch + 6], e6, acc);
                acc = fmaf(z[8 * ch + 7], e7, acc);
            }
            const float en = __fadd_rn(
                __fadd_rn(__fadd_rn(rr[0], rr[1]), __fadd_rn(rr[2], rr[3])),
                __fadd_rn(__fadd_rn(rr[4], rr[5]), __fadd_rn(rr[6], rr[7])));
            const float sc = __fsub_rn(__fadd_rn(znorm, en), __fmul_rn(2.0f, acc));
            if (sc < best || (sc == best && k < bk)) { best = sc; bk = k; }
        }
        cbs[cl * 256 + p] = best;
        cbk[cl * 256 + p] = bk;
    }
    __syncthreads();

    // ---- lex-(score,k) merge of 4 partials, write idx ----
    if (t < 256) {
        float best = cbs[t]; int bk = cbk[t];
        #pragma unroll
        for (int i = 1; i < 4; ++i) {
            const float sc = cbs[i * 256 + t]; const int k = cbk[i * 256 + t];
            if (sc < best || (sc == best && k < bk)) { best = sc; bk = k; }
        }
        kch[t] = bk;
        out_idxf[n0 + t] = (float)bk;
    }
    __syncthreads();

    // ---- epilogue: 1024 threads, dims split 4 ways (h = t>>8, 16 dims) ----
    {
        const int p = t & 255, h = t >> 8;
        const int bk = kch[p];
        const float* er = emb + bk * 64 + h * 16;
        const float* zp = ze + gbase + p + (h * 16) * 4096;
        float* op = out_zq + gbase + p + (h * 16) * 4096;
        float ls = 0.0f;
        #pragma unroll
        for (int j = 0; j < 16; ++j) {
            const float qv = er[j];
            const float zv = zp[j * 4096];
            op[j * 4096] = qv;
            const float d = qv - zv;
            ls = fmaf(d, d, ls);
        }
        #pragma unroll
        for (int off = 32; off > 0; off >>= 1) ls += __shfl_down(ls, off, 64);
        if (lane == 0) atomicAdd(loss, ls);
    }

    // ---- last block finalizes loss (device-scope atomics) ----
    __syncthreads();
    if (t == 0) {
        __threadfence();
        int old = atomicAdd(done, 1);
        if (old == (int)gridDim.x - 1) {
            __threadfence();
            float total = atomicAdd(loss, 0.0f);   // coherent read
            *out_loss = 1.25f * total / 4194304.0f;
        }
    }
}

extern "C" void kernel_launch(void* const* d_in, const int* in_sizes, int n_in,
                              void* d_out, int out_size, void* d_ws, size_t ws_size,
                              hipStream_t stream)
{
    const float* ze  = (const float*)d_in[0];   // (16,64,64,64) fp32
    const float* emb = (const float*)d_in[1];   // (1024,64) fp32
    float* out = (float*)d_out;
    float* out_zq   = out;                 // 4194304
    float* out_loss = out + 4194304;       // 1
    float* out_idxf = out + 4194305;       // 65536

    char* w = (char*)d_ws;
    float*          ws_loss = (float*)(w + WS_LOSS);
    int*            ws_done = (int*)(w + WS_DONE);
    unsigned short* ebf     = (unsigned short*)(w + WS_EBF);

    // allow >64KB dynamic LDS (no-op if already permitted)
    static bool attr_set = false;
    if (!attr_set) {
        hipFuncSetAttribute((const void*)vq_kernel,
                            hipFuncAttributeMaxDynamicSharedMemorySize, L_TOTAL);
        attr_set = true;
    }

    prep_kernel<<<4, 256, 0, stream>>>(emb, ebf, ws_loss, ws_done);
    vq_kernel<<<256, 1024, L_TOTAL, stream>>>(ze, emb, ebf, out_zq, out_idxf,
                                              ws_loss, ws_done, out_loss);
}

// Round 5
// 139.975 us; speedup vs baseline: 1.1589x; 1.1439x over previous
//
#include <hip/hip_runtime.h>

typedef short bf16x8 __attribute__((ext_vector_type(8)));
typedef float f32x4  __attribute__((ext_vector_type(4)));

#define CAP 12

// ws layout (bytes)
#define WS_LOSS 0
#define WS_DONE 8
#define WS_EN   64       // 1024 f32 codebook norms = 4096 B
#define WS_EBF  4160     // 1024*64 bf16 (permuted) = 131072 B

// dynamic LDS carve (bytes) — 143 KB, 1 block/CU (8 waves = 2/SIMD)
#define L_EBF    0        // 131072
#define L_MARG   131072   // 256*4 = 1024
#define L_CCNT   132096   // 1024
#define L_KCH    133120   // 1024
#define L_CSLOT  134144   // 256*CAP*4 = 12288
#define L_TOTAL  146432

__device__ __forceinline__ unsigned short f2bf(float f) {
    unsigned u = __float_as_uint(f);
    return (unsigned short)((u + 0x7fffu + ((u >> 16) & 1u)) >> 16);  // RTNE
}

// numpy pairwise sum (n=64): 8 accumulators, ((r0+r1)+(r2+r3))+((r4+r5)+(r6+r7)).
__device__ __forceinline__ float np_pairwise_sumsq64(const float* a) {
    float r[8];
    #pragma unroll
    for (int j = 0; j < 8; ++j) r[j] = __fmul_rn(a[j], a[j]);
    #pragma unroll
    for (int i = 8; i < 64; i += 8)
        #pragma unroll
        for (int j = 0; j < 8; ++j)
            r[j] = __fadd_rn(r[j], __fmul_rn(a[i + j], a[i + j]));
    return __fadd_rn(
        __fadd_rn(__fadd_rn(r[0], r[1]), __fadd_rn(r[2], r[3])),
        __fadd_rn(__fadd_rn(r[4], r[5]), __fadd_rn(r[6], r[7])));
}

// K1: bf16 codebook in MFMA-B-fragment-permuted layout + per-code exact fp32
// norms (bit-identical np_pairwise order) + zero loss/done.
// ebf[tile(64)][chunk j(8)][row r(16)][8 bf16], code = tile*16+r.
__global__ __launch_bounds__(256) void prep_kernel(
    const float* __restrict__ emb, unsigned short* __restrict__ ebf,
    float* __restrict__ en_t,
    float* __restrict__ loss, int* __restrict__ done)
{
    int k = blockIdx.x * 256 + threadIdx.x;
    if (k == 0) { *loss = 0.0f; *done = 0; }
    if (k < 1024) {
        float e[64];
        #pragma unroll
        for (int l = 0; l < 64; ++l) e[l] = emb[k * 64 + l];
        en_t[k] = np_pairwise_sumsq64(e);      // bit-exact numpy enorm
        int tile = k >> 4, r = k & 15;
        #pragma unroll
        for (int j = 0; j < 8; ++j) {
            bf16x8 v;
            #pragma unroll
            for (int m = 0; m < 8; ++m) v[m] = (short)f2bf(e[j * 8 + m]);
            *(bf16x8*)(ebf + tile * 1024 + j * 128 + r * 8) = v;
        }
    }
}

// K2: fused VQ — instruction-count-minimized R0 structure.
// 512 thr (8 waves), 256 pos/block, grid 256. Wave wv owns 32 positions x ALL
// 1024 codes: A-build redundancy 1x, rowmax is pure in-wave shfl (no LDS
// merge, one fewer barrier). Margin folded into A-build (same loaded values).
// Codebook staged via proven bf16x8 vector-load copy (R4's global_load_lds
// variant crashed the container; reverted to the R0-proven path).
// Cross-round evidence: VALUBusy pinned ~12% at any occupancy -> time tracks
// total VALU instruction count; this cuts ~40% of it vs R0.
__global__ __launch_bounds__(512, 2)
void vq_kernel(
    const float* __restrict__ ze, const float* __restrict__ emb,
    const unsigned short* __restrict__ ebf, const float* __restrict__ en_t,
    float* __restrict__ out_zq, float* __restrict__ out_idxf,
    float* __restrict__ loss, int* __restrict__ done,
    float* __restrict__ out_loss)
{
    extern __shared__ char smem[];
    unsigned short* ebf_l = (unsigned short*)(smem + L_EBF);
    float*          marg_l= (float*)(smem + L_MARG);
    int*            ccnt  = (int*)(smem + L_CCNT);
    int*            kch   = (int*)(smem + L_KCH);
    int*            cslot = (int*)(smem + L_CSLOT);

    const int t = threadIdx.x;
    const int n0 = blockIdx.x * 256;
    const int gbase = (n0 >> 12) * 262144 + (n0 & 4095);

    // ---- stage codebook -> LDS (512 thr x 16 x 16B vector copies) ----
    {
        const bf16x8* src = (const bf16x8*)ebf;
        bf16x8* dst = (bf16x8*)ebf_l;
        #pragma unroll 16
        for (int i = 0; i < 16; ++i) dst[t + i * 512] = src[t + i * 512];
    }

    // ---- A-fragments from global ze (L3-hot) + folded margin ----
    const int wv = t >> 6, lane = t & 63;
    const int r = lane & 15, q = lane >> 4;
    const int wp = wv * 32;                    // wave's 32 positions
    bf16x8 a[2][2];
    float sm[2] = {0.f, 0.f};
    #pragma unroll
    for (int rg = 0; rg < 2; ++rg) {
        const float* zb = ze + gbase + wp + rg * 16 + r;
        #pragma unroll
        for (int j = 0; j < 8; ++j) {
            const float v0 = zb[(q * 8 + j) * 4096];
            const float v1 = zb[(32 + q * 8 + j) * 4096];
            a[rg][0][j] = (short)f2bf(v0);
            a[rg][1][j] = (short)f2bf(v1);
            sm[rg] += fabsf(v0) + fabsf(v1);
        }
    }
    // margin: reduce |z|-partials over the 4 q-lane groups; q==0 lanes publish
    #pragma unroll
    for (int rg = 0; rg < 2; ++rg) {
        float s = sm[rg];
        s += __shfl_xor(s, 16, 64);
        s += __shfl_xor(s, 32, 64);
        if (q == 0) marg_l[wp + rg * 16 + r] = 1.67e-5f * s + 2.0e-4f;
    }
    if (t < 256) ccnt[t] = 0;
    __syncthreads();   // staging + marg + ccnt visible

    const unsigned short* bptr = ebf_l + q * 128 + r * 8;

    // ---- pass 1: per-row max of c = z.e over ALL 1024 codes (64 tiles) ----
    float rm[8];
    #pragma unroll
    for (int i = 0; i < 8; ++i) rm[i] = -1e30f;
    {
        bf16x8 pb0[4], pb1[4];
        #pragma unroll
        for (int i = 0; i < 4; ++i) {
            pb0[i] = *(const bf16x8*)(bptr + i * 1024);
            pb1[i] = *(const bf16x8*)(bptr + i * 1024 + 512);
        }
        #pragma unroll 4
        for (int tile = 0; tile < 64; ++tile) {
            bf16x8 b0 = pb0[tile & 3], b1 = pb1[tile & 3];
            int nt = tile + 4; if (nt > 63) nt = 63;
            pb0[tile & 3] = *(const bf16x8*)(bptr + nt * 1024);
            pb1[tile & 3] = *(const bf16x8*)(bptr + nt * 1024 + 512);
            #pragma unroll
            for (int rg = 0; rg < 2; ++rg) {
                f32x4 c = {0.f, 0.f, 0.f, 0.f};
                c = __builtin_amdgcn_mfma_f32_16x16x32_bf16(a[rg][0], b0, c, 0, 0, 0);
                c = __builtin_amdgcn_mfma_f32_16x16x32_bf16(a[rg][1], b1, c, 0, 0, 0);
                #pragma unroll
                for (int i = 0; i < 4; ++i)
                    rm[rg * 4 + i] = fmaxf(rm[rg * 4 + i], c[i]);
            }
        }
    }
    // in-wave rowmax: reduce over the 16 code-lanes (no LDS, no barrier)
    #pragma unroll
    for (int j = 0; j < 8; ++j) {
        float v = rm[j];
        v = fmaxf(v, __shfl_xor(v, 1, 16));
        v = fmaxf(v, __shfl_xor(v, 2, 16));
        v = fmaxf(v, __shfl_xor(v, 4, 16));
        v = fmaxf(v, __shfl_xor(v, 8, 16));
        rm[j] = v;
    }
    // threshold: candidate iff c >= maxc - marg/2
    float thr[8];
    #pragma unroll
    for (int j = 0; j < 8; ++j) {
        const int row = wp + (j >> 2) * 16 + q * 4 + (j & 3);
        thr[j] = rm[j] - 0.5f * marg_l[row];
    }

    // ---- pass 2: collect candidates (wave-private rows; LDS atomics) ----
    {
        bf16x8 pb0[4], pb1[4];
        #pragma unroll
        for (int i = 0; i < 4; ++i) {
            pb0[i] = *(const bf16x8*)(bptr + i * 1024);
            pb1[i] = *(const bf16x8*)(bptr + i * 1024 + 512);
        }
        #pragma unroll 4
        for (int tile = 0; tile < 64; ++tile) {
            bf16x8 b0 = pb0[tile & 3], b1 = pb1[tile & 3];
            int nt = tile + 4; if (nt > 63) nt = 63;
            pb0[tile & 3] = *(const bf16x8*)(bptr + nt * 1024);
            pb1[tile & 3] = *(const bf16x8*)(bptr + nt * 1024 + 512);
            const int code = tile * 16 + r;
            #pragma unroll
            for (int rg = 0; rg < 2; ++rg) {
                f32x4 c = {0.f, 0.f, 0.f, 0.f};
                c = __builtin_amdgcn_mfma_f32_16x16x32_bf16(a[rg][0], b0, c, 0, 0, 0);
                c = __builtin_amdgcn_mfma_f32_16x16x32_bf16(a[rg][1], b1, c, 0, 0, 0);
                #pragma unroll
                for (int i = 0; i < 4; ++i) {
                    if (c[i] >= thr[rg * 4 + i]) {
                        const int pp = wp + rg * 16 + q * 4 + i;
                        const int ci = atomicAdd(&ccnt[pp], 1);
                        if (ci < CAP) cslot[pp * CAP + ci] = code;
                    }
                }
            }
        }
    }
    __syncthreads();

    // ---- exact fp32 numpy rescore, 2 threads/position (candidate-strided);
    // enorm from precomputed table; dot in sequential numpy sgemm order.
    {
        const int p = t >> 1, cl = t & 1;
        int cnt = ccnt[p]; if (cnt > CAP) cnt = CAP;
        float z[64];
        const float* zp = ze + gbase + p;
        #pragma unroll
        for (int l = 0; l < 64; ++l) z[l] = zp[l * 4096];   // L3-hot reload
        const float znorm = np_pairwise_sumsq64(z);
        float best = 1e30f; int bk = 1 << 20;
        for (int c = cl; c < cnt; c += 2) {
            const int k = cslot[p * CAP + c];
            const float4* er = (const float4*)(emb + k * 64);
            float acc = 0.0f;
            #pragma unroll
            for (int jj = 0; jj < 16; ++jj) {
                const float4 v = er[jj];
                acc = fmaf(z[4 * jj + 0], v.x, acc);
                acc = fmaf(z[4 * jj + 1], v.y, acc);
                acc = fmaf(z[4 * jj + 2], v.z, acc);
                acc = fmaf(z[4 * jj + 3], v.w, acc);
            }
            const float sc = __fsub_rn(__fadd_rn(znorm, en_t[k]), __fmul_rn(2.0f, acc));
            if (sc < best || (sc == best && k < bk)) { best = sc; bk = k; }
        }
        // lex-(score,k) pair merge via shfl (adjacent lanes share a position)
        const float ob = __shfl_xor(best, 1, 64);
        const int   ok = __shfl_xor(bk, 1, 64);
        if (ob < best || (ob == best && ok < bk)) { best = ob; bk = ok; }
        if (cl == 0) {
            kch[p] = bk;
            out_idxf[n0 + p] = (float)bk;
        }
    }
    __syncthreads();

    // ---- epilogue: 512 threads, dims split (h = t>>8, 32 dims each) ----
    {
        const int p = t & 255, h = t >> 8;
        const int bk = kch[p];
        const float* er = emb + bk * 64 + h * 32;
        const float* zp = ze + gbase + p + (h * 32) * 4096;
        float* op = out_zq + gbase + p + (h * 32) * 4096;
        float ls = 0.0f;
        #pragma unroll
        for (int j = 0; j < 32; ++j) {
            const float qv = er[j];
            const float zv = zp[j * 4096];
            op[j * 4096] = qv;
            const float d = qv - zv;
            ls = fmaf(d, d, ls);
        }
        #pragma unroll
        for (int off = 32; off > 0; off >>= 1) ls += __shfl_down(ls, off, 64);
        if (lane == 0) atomicAdd(loss, ls);
    }

    // ---- last block finalizes loss (device-scope atomics) ----
    __syncthreads();
    if (t == 0) {
        __threadfence();
        int old = atomicAdd(done, 1);
        if (old == (int)gridDim.x - 1) {
            __threadfence();
            float total = atomicAdd(loss, 0.0f);   // coherent read
            *out_loss = 1.25f * total / 4194304.0f;
        }
    }
}

extern "C" void kernel_launch(void* const* d_in, const int* in_sizes, int n_in,
                              void* d_out, int out_size, void* d_ws, size_t ws_size,
                              hipStream_t stream)
{
    const float* ze  = (const float*)d_in[0];   // (16,64,64,64) fp32
    const float* emb = (const float*)d_in[1];   // (1024,64) fp32
    float* out = (float*)d_out;
    float* out_zq   = out;                 // 4194304
    float* out_loss = out + 4194304;       // 1
    float* out_idxf = out + 4194305;       // 65536

    char* w = (char*)d_ws;
    float*          ws_loss = (float*)(w + WS_LOSS);
    int*            ws_done = (int*)(w + WS_DONE);
    float*          ws_en   = (float*)(w + WS_EN);
    unsigned short* ebf     = (unsigned short*)(w + WS_EBF);

    // allow >64KB dynamic LDS (no-op if already permitted)
    static bool attr_set = false;
    if (!attr_set) {
        hipFuncSetAttribute((const void*)vq_kernel,
                            hipFuncAttributeMaxDynamicSharedMemorySize, L_TOTAL);
        attr_set = true;
    }

    prep_kernel<<<4, 256, 0, stream>>>(emb, ebf, ws_en, ws_loss, ws_done);
    vq_kernel<<<256, 512, L_TOTAL, stream>>>(ze, emb, ebf, ws_en, out_zq,
                                             out_idxf, ws_loss, ws_done, out_loss);
}